// Round 1
// baseline (253.389 us; speedup 1.0000x reference)
//
#include <hip/hip_runtime.h>

#define HH 512
#define WW 512
#define NPLANE 48
#define TX 64
#define TY 32
#define HALO 5
#define KS 11
#define IR (TY + 2 * HALO)  // 42 intermediate rows

// Phase A: horizontal Gaussian blur of 5 channels (p, t, p^2, t^2, p*t) into LDS.
// Phase B: vertical blur + SSIM map + block reduction -> atomicAdd into ws.
__global__ __launch_bounds__(256, 2) void ssim_kernel(
    const float* __restrict__ pred, const float* __restrict__ target,
    float* __restrict__ ws_sum)
{
    __shared__ float sh[5][IR][TX];   // 5*42*64*4 = 53760 B
    __shared__ float red[4];

    // Gaussian weights (normalized), computed per-thread (one-time cost)
    float w[KS];
    float s = 0.f;
#pragma unroll
    for (int k = 0; k < KS; ++k) {
        float d = (float)(k - HALO);
        w[k] = __expf(-d * d * (1.0f / 4.5f));   // sigma=1.5 -> 2*sigma^2 = 4.5
        s += w[k];
    }
    float invs = 1.0f / s;
#pragma unroll
    for (int k = 0; k < KS; ++k) w[k] *= invs;

    const int tid = threadIdx.x;
    const int plane = blockIdx.z;
    const int tx0 = blockIdx.x * TX;
    const int ty0 = blockIdx.y * TY;
    const float* __restrict__ pp = pred + (size_t)plane * HH * WW;
    const float* __restrict__ tp = target + (size_t)plane * HH * WW;

    // ---- Phase A: horizontal blur (zero padding outside image) ----
    for (int i = tid; i < IR * TX; i += 256) {
        int rr = i >> 6;            // TX == 64
        int c = i & (TX - 1);
        int gy = ty0 + rr - HALO;
        int gx0 = tx0 + c - HALO;
        float hp = 0.f, ht = 0.f, hp2 = 0.f, ht2 = 0.f, hpt = 0.f;
        if (gy >= 0 && gy < HH) {
            const float* __restrict__ prow = pp + (size_t)gy * WW;
            const float* __restrict__ trow = tp + (size_t)gy * WW;
#pragma unroll
            for (int k = 0; k < KS; ++k) {
                int gx = gx0 + k;
                bool v = (gx >= 0) && (gx < WW);
                float p = v ? prow[gx] : 0.f;
                float t = v ? trow[gx] : 0.f;
                float gk = w[k];
                float gp = gk * p, gt = gk * t;
                hp += gp;
                ht += gt;
                hp2 = fmaf(gp, p, hp2);
                ht2 = fmaf(gt, t, ht2);
                hpt = fmaf(gp, t, hpt);
            }
        }
        sh[0][rr][c] = hp;
        sh[1][rr][c] = ht;
        sh[2][rr][c] = hp2;
        sh[3][rr][c] = ht2;
        sh[4][rr][c] = hpt;
    }
    __syncthreads();

    // ---- Phase B: vertical blur + SSIM ----
    // 256 threads = 64 cols x 4 row-groups of 8 rows
    const int col = tid & (TX - 1);
    const int r0 = (tid >> 6) * 8;

    float acc[5][8];
#pragma unroll
    for (int ch = 0; ch < 5; ++ch) {
        float win[18];
#pragma unroll
        for (int m = 0; m < 18; ++m) win[m] = sh[ch][r0 + m][col];
#pragma unroll
        for (int j = 0; j < 8; ++j) {
            float a = 0.f;
#pragma unroll
            for (int k = 0; k < KS; ++k) a = fmaf(w[k], win[j + k], a);
            acc[ch][j] = a;
        }
    }

    const float C1 = 1.0e-4f;   // 0.01^2
    const float C2 = 9.0e-4f;   // 0.03^2
    float lsum = 0.f;
#pragma unroll
    for (int j = 0; j < 8; ++j) {
        float mup = acc[0][j], mut = acc[1][j];
        float mupsq = mup * mup, mutsq = mut * mut, mucr = mup * mut;
        float sp2 = acc[2][j] - mupsq;
        float st2 = acc[3][j] - mutsq;
        float scr = acc[4][j] - mucr;
        float n1 = 2.f * mucr + C1;
        float n2 = 2.f * scr + C2;
        float d1 = mupsq + mutsq + C1;
        float d2 = sp2 + st2 + C2;
        lsum += __fdividef(n1 * n2, d1 * d2);
    }

    // wave (64-lane) shuffle reduction
#pragma unroll
    for (int off = 32; off > 0; off >>= 1) lsum += __shfl_down(lsum, off, 64);
    if ((tid & 63) == 0) red[tid >> 6] = lsum;
    __syncthreads();
    if (tid == 0) {
        float tot = red[0] + red[1] + red[2] + red[3];
        atomicAdd(ws_sum, tot);
    }
}

__global__ void finalize_kernel(const float* __restrict__ ws_sum,
                                float* __restrict__ out) {
    out[0] = 1.0f - ws_sum[0] * (1.0f / 12582912.0f);  // N = 16*3*512*512
}

extern "C" void kernel_launch(void* const* d_in, const int* in_sizes, int n_in,
                              void* d_out, int out_size, void* d_ws, size_t ws_size,
                              hipStream_t stream) {
    const float* pred = (const float*)d_in[0];
    const float* target = (const float*)d_in[1];
    float* out = (float*)d_out;
    float* ws = (float*)d_ws;

    hipMemsetAsync(ws, 0, sizeof(float), stream);  // graph-capturable
    dim3 grid(WW / TX, HH / TY, NPLANE);           // 8 x 16 x 48 = 6144 blocks
    ssim_kernel<<<grid, 256, 0, stream>>>(pred, target, ws);
    finalize_kernel<<<1, 1, 0, stream>>>(ws, out);
}